// Round 7
// baseline (338.699 us; speedup 1.0000x reference)
//
#include <hip/hip_runtime.h>
#include <hip/hip_bf16.h>
#include <cstdint>
#include <cstddef>

#define B_  4
#define T_  2048
#define D_  1024
#define H_  16
#define DK_ 64
#define M_  (B_ * T_)     // 8192 tokens
#define NT8 (D_ / 64)     // 16 K-tiles of BK=64

typedef __attribute__((ext_vector_type(8))) short bf16x8;   // MFMA A/B frag (4 VGPRs)
typedef __attribute__((ext_vector_type(4))) float f32x4;    // MFMA C/D frag

static __device__ __forceinline__ unsigned short f2bf(float f) {
    __hip_bfloat16 h = __float2bfloat16(f);
    unsigned short u;
    __builtin_memcpy(&u, &h, 2);
    return u;
}

static __device__ __forceinline__ unsigned int pk2bf(float a, float b) {
    __hip_bfloat162 h = __float22bfloat162_rn(make_float2(a, b));
    unsigned int u;
    __builtin_memcpy(&u, &h, 4);
    return u;
}

static __device__ __forceinline__ void gl2lds16(const void* g, void* l) {
    __builtin_amdgcn_global_load_lds(
        (const __attribute__((address_space(1))) unsigned int*)g,
        (__attribute__((address_space(3))) unsigned int*)l,
        16, 0, 0);
}

// ---------------------------------------------------------------------------
// fp32 -> bf16 convert: regions [x | wq | wk | wv | wo] -> contiguous dst.
// ---------------------------------------------------------------------------
__global__ __launch_bounds__(256) void cvt_bf16(
    const float* __restrict__ x,  const float* __restrict__ wq,
    const float* __restrict__ wk, const float* __restrict__ wv,
    const float* __restrict__ wo, unsigned short* __restrict__ dst)
{
    const int idx = blockIdx.x * 256 + threadIdx.x;   // vec4 index
    const float* src;
    int off;
    if (idx < 2097152) { src = x; off = idx; }
    else {
        const int r = (idx - 2097152) >> 18;
        off = (idx - 2097152) & 262143;
        src = (r == 0) ? wq : (r == 1) ? wk : (r == 2) ? wv : wo;
    }
    float4 v = ((const float4*)src)[off];
    ushort4 o;
    o.x = f2bf(v.x); o.y = f2bf(v.y); o.z = f2bf(v.z); o.w = f2bf(v.w);
    ((ushort4*)dst)[idx] = o;
}

// ---------------------------------------------------------------------------
// 256(M)x128(N) BK=64 MFMA GEMM, 2 phases/K-tile, counted vmcnt + setprio.
// (unchanged from round 3 -- see comments there)
// ---------------------------------------------------------------------------
__global__ __launch_bounds__(512, 2) void gemm8p(
    const unsigned short* __restrict__ Amat,
    const unsigned short* __restrict__ w0,
    const unsigned short* __restrict__ w1,
    const unsigned short* __restrict__ w2,
    const float* __restrict__ b0,
    const float* __restrict__ b1,
    const float* __restrict__ b2,
    unsigned short* __restrict__ outU,
    float* __restrict__ outF,
    const int mode)
{
    // bijective XCD swizzle: per XCD q: m-tiles {4q..4q+3}, (n,sel) major.
    const int s   = blockIdx.x;
    const int xcd = s & 7;
    const int idx = s >> 3;
    const int mm  = idx & 3;
    const int ns  = idx >> 2;                 // mode0: 0..23, mode1: 0..7
    const int sel = (mode == 0) ? (ns >> 3) : 3;
    const int nn  = (mode == 0) ? (ns & 7) : ns;
    const int m0  = (xcd * 4 + mm) * 256;
    const int n0  = nn * 128;

    const unsigned short* Bmat = (sel == 0) ? w0 : (sel == 1) ? w1 : w2;
    const float* bias          = (sel == 0) ? b0 : (sel == 1) ? b1 : b2;
    const bool selV = (sel == 2);

    const int tid  = threadIdx.x;
    const int w    = tid >> 6;
    const int lane = tid & 63;
    const int l15  = lane & 15, g = lane >> 4;
    const int lane8 = lane * 8;
    const int wm8  = (w >> 2) * 8;    // A frag tg base (M half)
    const int wn2  = (w & 3) * 2;     // B frag tg base (N quarter of 32)

    __shared__ __align__(16) unsigned short As[2][32][512];   // 64 KB
    __shared__ __align__(16) unsigned short Bs[2][16][512];   // 32 KB

    f32x4 acc[8][2];
#pragma unroll
    for (int i = 0; i < 8; ++i)
#pragma unroll
        for (int j = 0; j < 2; ++j) acc[i][j] = (f32x4){0.f, 0.f, 0.f, 0.f};

    // per-thread global addresses of the 6 staging roles (advance kt*64)
    const unsigned short* aP[4];
#pragma unroll
    for (int j = 0; j < 4; ++j)
        aP[j] = Amat + (size_t)(m0 + (w >> 1) * 16 + 64 * j + l15) * D_
                     + (w & 1) * 32 + g * 8;
    const unsigned short* bP[2];
#pragma unroll
    for (int jb = 0; jb < 2; ++jb)
        bP[jb] = Bmat + (size_t)(n0 + w * 16 + l15) * D_ + jb * 32 + g * 8;

    // ---- prologue: K0 all 6 roles; K1 first set {A0,A2,B0,B1} ----
#pragma unroll
    for (int j = 0; j < 4; ++j) gl2lds16(aP[j], &As[0][w + 8 * j][0]);
    gl2lds16(bP[0], &Bs[0][2 * w    ][0]);
    gl2lds16(bP[1], &Bs[0][2 * w + 1][0]);
    gl2lds16(aP[0] + 64, &As[1][w     ][0]);
    gl2lds16(aP[2] + 64, &As[1][w + 16][0]);
    gl2lds16(bP[0] + 64, &Bs[1][2 * w    ][0]);
    gl2lds16(bP[1] + 64, &Bs[1][2 * w + 1][0]);
    asm volatile("s_waitcnt vmcnt(4)" ::: "memory");   // K0 landed
    __builtin_amdgcn_s_barrier();

    bf16x8 bfr[2][2];
    bf16x8 ap[4][2];

    for (int kt = 0; kt < NT8; ++kt) {
        const int cur = kt & 1;
        const int ko  = kt * 64;

        // ---------- phase 0: B frags + A mi0-3; stage kt+1 {A1,A3} ----------
#pragma unroll
        for (int nj = 0; nj < 2; ++nj)
#pragma unroll
            for (int ks = 0; ks < 2; ++ks)
                bfr[nj][ks] = *(const bf16x8*)&Bs[cur][(wn2 + nj) * 2 + ks][lane8];
#pragma unroll
        for (int mi = 0; mi < 4; ++mi)
#pragma unroll
            for (int ks = 0; ks < 2; ++ks)
                ap[mi][ks] = *(const bf16x8*)&As[cur][(wm8 + mi) * 2 + ks][lane8];
        if (kt + 1 < NT8) {
            gl2lds16(aP[1] + ko + 64, &As[cur ^ 1][w + 8 ][0]);
            gl2lds16(aP[3] + ko + 64, &As[cur ^ 1][w + 24][0]);
        }
        __builtin_amdgcn_s_barrier();
        asm volatile("s_waitcnt lgkmcnt(0)" ::: "memory");
        __builtin_amdgcn_s_setprio(1);
        if (!selV) {
#pragma unroll
            for (int mi = 0; mi < 4; ++mi)
#pragma unroll
                for (int nj = 0; nj < 2; ++nj) {
                    acc[mi][nj] = __builtin_amdgcn_mfma_f32_16x16x32_bf16(
                        bfr[nj][0], ap[mi][0], acc[mi][nj], 0, 0, 0);
                    acc[mi][nj] = __builtin_amdgcn_mfma_f32_16x16x32_bf16(
                        bfr[nj][1], ap[mi][1], acc[mi][nj], 0, 0, 0);
                }
        } else {
#pragma unroll
            for (int mi = 0; mi < 4; ++mi)
#pragma unroll
                for (int nj = 0; nj < 2; ++nj) {
                    acc[mi][nj] = __builtin_amdgcn_mfma_f32_16x16x32_bf16(
                        ap[mi][0], bfr[nj][0], acc[mi][nj], 0, 0, 0);
                    acc[mi][nj] = __builtin_amdgcn_mfma_f32_16x16x32_bf16(
                        ap[mi][1], bfr[nj][1], acc[mi][nj], 0, 0, 0);
                }
        }
        __builtin_amdgcn_s_setprio(0);
        __builtin_amdgcn_s_barrier();

        // ---------- phase 1: A mi4-7; stage kt+2 {A0,A2,B0,B1} ----------
#pragma unroll
        for (int mi = 0; mi < 4; ++mi)
#pragma unroll
            for (int ks = 0; ks < 2; ++ks)
                ap[mi][ks] = *(const bf16x8*)&As[cur][(wm8 + 4 + mi) * 2 + ks][lane8];
        if (kt + 2 < NT8) {
            gl2lds16(aP[0] + ko + 128, &As[cur][w     ][0]);
            gl2lds16(aP[2] + ko + 128, &As[cur][w + 16][0]);
            gl2lds16(bP[0] + ko + 128, &Bs[cur][2 * w    ][0]);
            gl2lds16(bP[1] + ko + 128, &Bs[cur][2 * w + 1][0]);
        }
        __builtin_amdgcn_s_barrier();
        asm volatile("s_waitcnt lgkmcnt(0)" ::: "memory");
        __builtin_amdgcn_s_setprio(1);
        if (!selV) {
#pragma unroll
            for (int mi = 0; mi < 4; ++mi)
#pragma unroll
                for (int nj = 0; nj < 2; ++nj) {
                    acc[4 + mi][nj] = __builtin_amdgcn_mfma_f32_16x16x32_bf16(
                        bfr[nj][0], ap[mi][0], acc[4 + mi][nj], 0, 0, 0);
                    acc[4 + mi][nj] = __builtin_amdgcn_mfma_f32_16x16x32_bf16(
                        bfr[nj][1], ap[mi][1], acc[4 + mi][nj], 0, 0, 0);
                }
        } else {
#pragma unroll
            for (int mi = 0; mi < 4; ++mi)
#pragma unroll
                for (int nj = 0; nj < 2; ++nj) {
                    acc[4 + mi][nj] = __builtin_amdgcn_mfma_f32_16x16x32_bf16(
                        ap[mi][0], bfr[nj][0], acc[4 + mi][nj], 0, 0, 0);
                    acc[4 + mi][nj] = __builtin_amdgcn_mfma_f32_16x16x32_bf16(
                        ap[mi][1], bfr[nj][1], acc[4 + mi][nj], 0, 0, 0);
                }
        }
        __builtin_amdgcn_s_setprio(0);
        if (kt < NT8 - 2)       asm volatile("s_waitcnt vmcnt(4)" ::: "memory");
        else if (kt == NT8 - 2) asm volatile("s_waitcnt vmcnt(0)" ::: "memory");
        __builtin_amdgcn_s_barrier();
    }

    // ---- epilogue ----
    const int mbase = m0 + (w >> 2) * 128;
    const int nbase = n0 + (w & 3) * 32;
    const size_t BTD = (size_t)B_ * T_ * D_;

    if (mode == 1) {
        // out-proj: fp32, token = l15, channel = g*4+reg
#pragma unroll
        for (int nj = 0; nj < 2; ++nj) {
            const int ch0 = nbase + nj * 16 + g * 4;
            const float4 bb = *(const float4*)(bias + ch0);
#pragma unroll
            for (int mi = 0; mi < 8; ++mi) {
                const int tok = mbase + mi * 16 + l15;
                float4 r;
                r.x = acc[mi][nj][0] + bb.x;
                r.y = acc[mi][nj][1] + bb.y;
                r.z = acc[mi][nj][2] + bb.z;
                r.w = acc[mi][nj][3] + bb.w;
                *(float4*)(outF + (size_t)tok * D_ + ch0) = r;
            }
        }
    } else if (!selV) {
        // Q/K: [bh][t][dk], token = l15, channel = g*4+reg; Q pre-scaled
        unsigned short* outp = outU + (size_t)sel * BTD;
        const float osc = (sel == 0) ? 0.125f * 1.44269504f : 1.0f;
#pragma unroll
        for (int nj = 0; nj < 2; ++nj) {
            const int ch0 = nbase + nj * 16 + g * 4;
            const int hh = ch0 >> 6, dk0 = ch0 & 63;
            const float4 bb = *(const float4*)(bias + ch0);
#pragma unroll
            for (int mi = 0; mi < 8; ++mi) {
                const int tok = mbase + mi * 16 + l15;
                const int b = tok >> 11, t = tok & (T_ - 1);
                ushort4 r;
                r.x = f2bf((acc[mi][nj][0] + bb.x) * osc);
                r.y = f2bf((acc[mi][nj][1] + bb.y) * osc);
                r.z = f2bf((acc[mi][nj][2] + bb.z) * osc);
                r.w = f2bf((acc[mi][nj][3] + bb.w) * osc);
                *(ushort4*)(outp + ((size_t)((b * H_ + hh) * T_ + t)) * DK_ + dk0) = r;
            }
        }
    } else {
        // V^T: [bh][dk][t], channel = l15, token = g*4+reg
        unsigned short* outp = outU + 2 * BTD;
#pragma unroll
        for (int nj = 0; nj < 2; ++nj) {
            const int ch = nbase + nj * 16 + l15;
            const int hh = ch >> 6, dk = ch & 63;
            const float bbv = bias[ch];
#pragma unroll
            for (int mi = 0; mi < 8; ++mi) {
                const int tok0 = mbase + mi * 16 + g * 4;
                const int b = tok0 >> 11, t0 = tok0 & (T_ - 1);
                ushort4 r;
                r.x = f2bf(acc[mi][nj][0] + bbv);
                r.y = f2bf(acc[mi][nj][1] + bbv);
                r.z = f2bf(acc[mi][nj][2] + bbv);
                r.w = f2bf(acc[mi][nj][3] + bbv);
                *(ushort4*)(outp + ((size_t)((b * H_ + hh) * DK_ + dk)) * T_ + t0) = r;
            }
        }
    }
}

// ---------------------------------------------------------------------------
// MFMA flash attention, R7: 4 waves x 32 q (two 16-q tiles per wave), block
// q-span 128. Same chunk structure + XCD-pinned mapping as R6 (FETCH-verified)
// but: two independent QK->exp2->PV chains per wave share each K/V ds_read
// (2x ILP, 2x fewer ds_reads per MFMA), and block-chunk total halves
// (272 vs 528 per bh) so barrier + staging overhead halves at constant MFMA.
// Waves fully past the diagonal skip compute (barriers stay uniform).
// 24 blocks/bh: x=0..7 single-split (q 0..1023), x=8..15 two key-splits.
// LDS 33.8 KB -> 4 blocks/CU. Light blocks scheduled last (tail-friendly).
// ---------------------------------------------------------------------------
__global__ __launch_bounds__(256) void attn(
    const unsigned short* __restrict__ qg, const unsigned short* __restrict__ kg,
    const unsigned short* __restrict__ vtg,
    float* __restrict__ pO, float* __restrict__ pL,
    unsigned short* __restrict__ yh)
{
    // XCD-pinned mapping: xcd = s&7 owns bh in {xcd*8..xcd*8+7}, bh-major,
    // heavy-first within bh.
    const int s    = blockIdx.x;          // 0..1535
    const int xcd  = s & 7;
    const int t_   = s >> 3;              // 0..191
    const int bhl  = t_ / 24;             // 0..7
    const int j    = t_ % 24;
    const int bh   = xcd * 8 + bhl;
    const int ridx = 23 - j;              // heavy-first

    int x, ks;
    if (ridx < 8) { x = ridx; ks = 0; }
    else { const int r = ridx - 8; x = 8 + (r >> 1); ks = r & 1; }
    const int h   = bh & (H_ - 1);
    const int b   = bh >> 4;
    const int tq0 = x * 128;
    const int sBeg = ks << 10;                            // ks * 1024
    const int sEnd = min(sBeg + 1024, tq0 + 128);
    const int nCh  = (sEnd - sBeg) >> 6;                  // 2..16 chunks

    const int tid  = threadIdx.x;
    const int w    = tid >> 6;
    const int lane = tid & 63;
    const int l15  = lane & 15;
    const int g    = lane >> 4;

    const size_t base = (size_t)bh * T_ * DK_;
    const unsigned short* Qb  = qg  + base;   // [t][dk], pre-scaled
    const unsigned short* Kb  = kg  + base;   // [t][dk]
    const unsigned short* Vtb = vtg + base;   // [dk][t]

    __shared__ __align__(16) unsigned short Kf[8][512];     // 8 KB
    __shared__ __align__(16) unsigned short Vf[8][512];     // 8 KB
    __shared__ __align__(16) unsigned short Pb[4][32][68];  // 17.4 KB

    const int q0w = tq0 + w * 32;             // wave owns q0w..q0w+31
    const int tqa = q0w + l15;                // tile a
    const int tqb = q0w + 16 + l15;           // tile b

    bf16x8 qfa0 = *(const bf16x8*)(Qb + (size_t)tqa * DK_ + g * 8);
    bf16x8 qfa1 = *(const bf16x8*)(Qb + (size_t)tqa * DK_ + 32 + g * 8);
    bf16x8 qfb0 = *(const bf16x8*)(Qb + (size_t)tqb * DK_ + g * 8);
    bf16x8 qfb1 = *(const bf16x8*)(Qb + (size_t)tqb * DK_ + 32 + g * 8);

    // all-ones A fragment (bf16 1.0 = 0x3F80) for the l-sum MFMA
    bf16x8 ones;
#pragma unroll
    for (int jj = 0; jj < 8; ++jj) ones[jj] = (short)0x3F80;

    f32x4 oa[4], ob[4];
#pragma unroll
    for (int i = 0; i < 4; ++i) {
        oa[i] = (f32x4){0.f, 0.f, 0.f, 0.f};
        ob[i] = (f32x4){0.f, 0.f, 0.f, 0.f};
    }
    f32x4 lacca = {0.f, 0.f, 0.f, 0.f};
    f32x4 laccb = {0.f, 0.f, 0.f, 0.f};

    // wave w stages K s-tile st=w and V d-tile dt=w (both 32-wide halves)
    const unsigned short* kSrc = Kb + (size_t)(sBeg + w * 16 + l15) * DK_ + g * 8;
    const unsigned short* vSrc = Vtb + (size_t)(w * 16 + l15) * T_ + sBeg + g * 8;

    // preload chunk 0 into registers
    bf16x8 kr0 = *(const bf16x8*)(kSrc);
    bf16x8 kr1 = *(const bf16x8*)(kSrc + 32);
    bf16x8 vr0 = *(const bf16x8*)(vSrc);
    bf16x8 vr1 = *(const bf16x8*)(vSrc + 32);

    for (int ch = 0; ch < nCh; ++ch) {
        const int s0 = sBeg + ch * 64;
        __syncthreads();                       // previous chunk fully consumed
        *(bf16x8*)&Kf[2 * w    ][lane * 8] = kr0;
        *(bf16x8*)&Kf[2 * w + 1][lane * 8] = kr1;
        *(bf16x8*)&Vf[2 * w    ][lane * 8] = vr0;
        *(bf16x8*)&Vf[2 * w + 1][lane * 8] = vr1;
        if (ch + 1 < nCh) {                    // loads stay in flight across barrier
            const size_t ko = (size_t)(ch + 1) * 64 * DK_;
            const int    vo = (ch + 1) * 64;
            kr0 = *(const bf16x8*)(kSrc + ko);
            kr1 = *(const bf16x8*)(kSrc + ko + 32);
            vr0 = *(const bf16x8*)(vSrc + vo);
            vr1 = *(const bf16x8*)(vSrc + vo + 32);
        }
        __syncthreads();                       // staged data visible

        if (s0 > q0w + 31) continue;           // wave fully past diagonal (no barrier inside)

#pragma unroll
        for (int st = 0; st < 4; ++st) {
            const int sbase = s0 + st * 16;
            bf16x8 a0 = *(const bf16x8*)&Kf[st * 2 + 0][lane * 8];
            bf16x8 a1 = *(const bf16x8*)&Kf[st * 2 + 1][lane * 8];
            uint2 pka; pka.x = 0u; pka.y = 0u;
            uint2 pkb; pkb.x = 0u; pkb.y = 0u;
            if (sbase <= q0w + 15) {           // tile a live
                f32x4 sacc = {0.f, 0.f, 0.f, 0.f};
                sacc = __builtin_amdgcn_mfma_f32_16x16x32_bf16(a0, qfa0, sacc, 0, 0, 0);
                sacc = __builtin_amdgcn_mfma_f32_16x16x32_bf16(a1, qfa1, sacc, 0, 0, 0);
                float p0, p1, p2, p3;
                if (sbase + 15 > q0w) {        // diagonal tile: per-entry mask
                    p0 = (sbase + g * 4 + 0 <= tqa) ? exp2f(sacc[0]) : 0.f;
                    p1 = (sbase + g * 4 + 1 <= tqa) ? exp2f(sacc[1]) : 0.f;
                    p2 = (sbase + g * 4 + 2 <= tqa) ? exp2f(sacc[2]) : 0.f;
                    p3 = (sbase + g * 4 + 3 <= tqa) ? exp2f(sacc[3]) : 0.f;
                } else {
                    p0 = exp2f(sacc[0]); p1 = exp2f(sacc[1]);
                    p2 = exp2f(sacc[2]); p3 = exp2f(sacc[3]);
                }
                pka.x = pk2bf(p0, p1);
                pka.y = pk2bf(p2, p3);
            }
            {                                  // tile b live (s0 <= q0w+31 given)
                f32x4 sacc = {0.f, 0.f, 0.f, 0.f};
                sacc = __builtin_amdgcn_mfma_f32_16x16x32_bf16(a0, qfb0, sacc, 0, 0, 0);
                sacc = __builtin_amdgcn_mfma_f32_16x16x32_bf16(a1, qfb1, sacc, 0, 0, 0);
                float p0, p1, p2, p3;
                if (sbase + 15 > q0w + 16) {   // diagonal tile for b
                    p0 = (sbase + g * 4 + 0 <= tqb) ? exp2f(sacc[0]) : 0.f;
                    p1 = (sbase + g * 4 + 1 <= tqb) ? exp2f(sacc[1]) : 0.f;
                    p2 = (sbase + g * 4 + 2 <= tqb) ? exp2f(sacc[2]) : 0.f;
                    p3 = (sbase + g * 4 + 3 <= tqb) ? exp2f(sacc[3]) : 0.f;
                } else {
                    p0 = exp2f(sacc[0]); p1 = exp2f(sacc[1]);
                    p2 = exp2f(sacc[2]); p3 = exp2f(sacc[3]);
                }
                pkb.x = pk2bf(p0, p1);
                pkb.y = pk2bf(p2, p3);
            }
            *(uint2*)&Pb[w][l15     ][st * 16 + g * 4] = pka;   // P[q][s]
            *(uint2*)&Pb[w][16 + l15][st * 16 + g * 4] = pkb;
        }

        bf16x8 pa0 = *(const bf16x8*)&Pb[w][l15     ][g * 8];
        bf16x8 pa1 = *(const bf16x8*)&Pb[w][l15     ][32 + g * 8];
        bf16x8 pb0 = *(const bf16x8*)&Pb[w][16 + l15][g * 8];
        bf16x8 pb1 = *(const bf16x8*)&Pb[w][16 + l15][32 + g * 8];
        lacca = __builtin_amdgcn_mfma_f32_16x16x32_bf16(ones, pa0, lacca, 0, 0, 0);
        lacca = __builtin_amdgcn_mfma_f32_16x16x32_bf16(ones, pa1, lacca, 0, 0, 0);
        laccb = __builtin_amdgcn_mfma_f32_16x16x32_bf16(ones, pb0, laccb, 0, 0, 0);
        laccb = __builtin_amdgcn_mfma_f32_16x16x32_bf16(ones, pb1, laccb, 0, 0, 0);
#pragma unroll
        for (int dt = 0; dt < 4; ++dt) {
            bf16x8 v0 = *(const bf16x8*)&Vf[dt * 2 + 0][lane * 8];
            bf16x8 v1 = *(const bf16x8*)&Vf[dt * 2 + 1][lane * 8];
            oa[dt] = __builtin_amdgcn_mfma_f32_16x16x32_bf16(v0, pa0, oa[dt], 0, 0, 0);
            oa[dt] = __builtin_amdgcn_mfma_f32_16x16x32_bf16(v1, pa1, oa[dt], 0, 0, 0);
            ob[dt] = __builtin_amdgcn_mfma_f32_16x16x32_bf16(v0, pb0, ob[dt], 0, 0, 0);
            ob[dt] = __builtin_amdgcn_mfma_f32_16x16x32_bf16(v1, pb1, ob[dt], 0, 0, 0);
        }
    }

    if (tq0 < 1024) {
        // single split: normalize and write yh bf16 directly (both tiles)
        const float inva = 1.f / lacca[0];
        const float invb = 1.f / laccb[0];
        unsigned short* ya = yh + ((size_t)(b * T_ + tqa)) * D_ + h * DK_;
        unsigned short* yb = yh + ((size_t)(b * T_ + tqb)) * D_ + h * DK_;
#pragma unroll
        for (int dt = 0; dt < 4; ++dt) {
            ushort4 ra, rb;
            ra.x = f2bf(oa[dt][0] * inva); ra.y = f2bf(oa[dt][1] * inva);
            ra.z = f2bf(oa[dt][2] * inva); ra.w = f2bf(oa[dt][3] * inva);
            rb.x = f2bf(ob[dt][0] * invb); rb.y = f2bf(ob[dt][1] * invb);
            rb.z = f2bf(ob[dt][2] * invb); rb.w = f2bf(ob[dt][3] * invb);
            *(ushort4*)(ya + dt * 16 + g * 4) = ra;
            *(ushort4*)(yb + dt * 16 + g * 4) = rb;
        }
    } else {
        // two splits: write fp32 partials for the reduce pass (both tiles)
        float* poa = pO + ((size_t)ks * (B_ * H_) + bh) * (size_t)T_ * DK_
                        + (size_t)tqa * DK_;
        float* pob = pO + ((size_t)ks * (B_ * H_) + bh) * (size_t)T_ * DK_
                        + (size_t)tqb * DK_;
#pragma unroll
        for (int dt = 0; dt < 4; ++dt) {
            float4 ra, rb;
            ra.x = oa[dt][0]; ra.y = oa[dt][1]; ra.z = oa[dt][2]; ra.w = oa[dt][3];
            rb.x = ob[dt][0]; rb.y = ob[dt][1]; rb.z = ob[dt][2]; rb.w = ob[dt][3];
            *(float4*)(poa + dt * 16 + g * 4) = ra;
            *(float4*)(pob + dt * 16 + g * 4) = rb;
        }
        if (g == 0) {
            pL[((size_t)ks * (B_ * H_) + bh) * T_ + tqa] = lacca[0];
            pL[((size_t)ks * (B_ * H_) + bh) * T_ + tqb] = laccb[0];
        }
    }
}

// ---------------------------------------------------------------------------
// Split-K reduce, t >= 1024 only (unchanged).
// ---------------------------------------------------------------------------
__global__ __launch_bounds__(256) void attn_reduce(
    const float* __restrict__ pO, const float* __restrict__ pL,
    unsigned short* __restrict__ yh)
{
    const int idx  = blockIdx.x * 256 + threadIdx.x;
    const int flat = idx * 4;
    const int dk = flat & 63;
    const int t  = 1024 + ((flat >> 6) & 1023);
    const int bh = flat >> 16;
    const int h = bh & (H_ - 1), b = bh >> 4;

    const size_t e0 = ((size_t)bh * T_ + t) * DK_ + dk;
    const size_t soff = (size_t)(B_ * H_) * T_ * DK_;
    float4 o  = *(const float4*)(pO + e0);
    float4 o1 = *(const float4*)(pO + soff + e0);
    o.x += o1.x; o.y += o1.y; o.z += o1.z; o.w += o1.w;
    const float l = pL[(size_t)bh * T_ + t]
                  + pL[(size_t)(B_ * H_) * T_ + (size_t)bh * T_ + t];
    const float inv = 1.f / l;
    ushort4 r;
    r.x = f2bf(o.x * inv); r.y = f2bf(o.y * inv);
    r.z = f2bf(o.z * inv); r.w = f2bf(o.w * inv);
    *(ushort4*)(yh + ((size_t)(b * T_ + t)) * D_ + h * DK_ + dk) = r;
}

// ---------------------------------------------------------------------------
extern "C" void kernel_launch(void* const* d_in, const int* in_sizes, int n_in,
                              void* d_out, int out_size, void* d_ws, size_t ws_size,
                              hipStream_t stream) {
    const float* x  = (const float*)d_in[0];
    const float* wq = (const float*)d_in[1];
    const float* bq = (const float*)d_in[2];
    const float* wk = (const float*)d_in[3];
    const float* bk = (const float*)d_in[4];
    const float* wv = (const float*)d_in[5];
    const float* bv = (const float*)d_in[6];
    const float* wo = (const float*)d_in[7];
    const float* bo = (const float*)d_in[8];
    float* out = (float*)d_out;

    const size_t BTD = (size_t)B_ * T_ * D_;          // 8388608
    const size_t WSZ = (size_t)D_ * D_;               // 1048576
    unsigned short* xb  = (unsigned short*)d_ws;      // [x | wq | wk | wv | wo] bf16
    unsigned short* wqb = xb  + BTD;
    unsigned short* wkb = wqb + WSZ;
    unsigned short* wvb = wkb + WSZ;
    unsigned short* wob = wvb + WSZ;
    unsigned short* qb  = wob + WSZ;                  // q | k | vt bf16
    unsigned short* kb  = qb  + BTD;
    unsigned short* vtb = kb  + BTD;
    unsigned short* yhb = vtb + BTD;                  // yh bf16 [B,T,D]
    float* pO = (float*)(yhb + BTD);                  // [2][bh][t][dk] fp32
    float* pL = pO + 2 * BTD;                         // [2][bh][t] fp32

    cvt_bf16<<<dim3(12288), 256, 0, stream>>>(x, wq, wk, wv, wo, xb);

    // QKV: 8 xcd-chunks x 4 m x (8 n x 3 sel) = 768 blocks = exactly 3 rounds
    gemm8p<<<dim3(768), 512, 0, stream>>>(
        xb, wqb, wkb, wvb, bq, bk, bv, qb, (float*)nullptr, 0);

    // attn: 1536 blocks (24 per bh), XCD-pinned bh-major mapping
    attn<<<dim3(1536), 256, 0, stream>>>(qb, kb, vtb, pO, pL, yhb);

    attn_reduce<<<dim3(4096), 256, 0, stream>>>(pO, pL, yhb);

    // out-proj: 8 x 4 x 8 = 256 blocks = exactly 1 round
    gemm8p<<<dim3(256), 512, 0, stream>>>(
        yhb, wob, wob, wob, bo, bo, bo, (unsigned short*)nullptr, out, 1);
}

// Round 8
// 319.150 us; speedup vs baseline: 1.0613x; 1.0613x over previous
//
#include <hip/hip_runtime.h>
#include <hip/hip_bf16.h>
#include <cstdint>
#include <cstddef>

#define B_  4
#define T_  2048
#define D_  1024
#define H_  16
#define DK_ 64
#define M_  (B_ * T_)     // 8192 tokens
#define NT8 (D_ / 64)     // 16 K-tiles of BK=64

typedef __attribute__((ext_vector_type(8))) short bf16x8;   // MFMA A/B frag (4 VGPRs)
typedef __attribute__((ext_vector_type(4))) float f32x4;    // MFMA C/D frag

static __device__ __forceinline__ unsigned short f2bf(float f) {
    __hip_bfloat16 h = __float2bfloat16(f);
    unsigned short u;
    __builtin_memcpy(&u, &h, 2);
    return u;
}

static __device__ __forceinline__ unsigned int pk2bf(float a, float b) {
    __hip_bfloat162 h = __float22bfloat162_rn(make_float2(a, b));
    unsigned int u;
    __builtin_memcpy(&u, &h, 4);
    return u;
}

static __device__ __forceinline__ void gl2lds16(const void* g, void* l) {
    __builtin_amdgcn_global_load_lds(
        (const __attribute__((address_space(1))) unsigned int*)g,
        (__attribute__((address_space(3))) unsigned int*)l,
        16, 0, 0);
}

// ---------------------------------------------------------------------------
// fp32 -> bf16 convert: regions [x | wq | wk | wv | wo] -> contiguous dst.
// ---------------------------------------------------------------------------
__global__ __launch_bounds__(256) void cvt_bf16(
    const float* __restrict__ x,  const float* __restrict__ wq,
    const float* __restrict__ wk, const float* __restrict__ wv,
    const float* __restrict__ wo, unsigned short* __restrict__ dst)
{
    const int idx = blockIdx.x * 256 + threadIdx.x;   // vec4 index
    const float* src;
    int off;
    if (idx < 2097152) { src = x; off = idx; }
    else {
        const int r = (idx - 2097152) >> 18;
        off = (idx - 2097152) & 262143;
        src = (r == 0) ? wq : (r == 1) ? wk : (r == 2) ? wv : wo;
    }
    float4 v = ((const float4*)src)[off];
    ushort4 o;
    o.x = f2bf(v.x); o.y = f2bf(v.y); o.z = f2bf(v.z); o.w = f2bf(v.w);
    ((ushort4*)dst)[idx] = o;
}

// ---------------------------------------------------------------------------
// 256(M)x128(N) BK=64 MFMA GEMM, 2 phases/K-tile, counted vmcnt + setprio.
// (unchanged from round 3 -- see comments there)
// ---------------------------------------------------------------------------
__global__ __launch_bounds__(512, 2) void gemm8p(
    const unsigned short* __restrict__ Amat,
    const unsigned short* __restrict__ w0,
    const unsigned short* __restrict__ w1,
    const unsigned short* __restrict__ w2,
    const float* __restrict__ b0,
    const float* __restrict__ b1,
    const float* __restrict__ b2,
    unsigned short* __restrict__ outU,
    float* __restrict__ outF,
    const int mode)
{
    // bijective XCD swizzle: per XCD q: m-tiles {4q..4q+3}, (n,sel) major.
    const int s   = blockIdx.x;
    const int xcd = s & 7;
    const int idx = s >> 3;
    const int mm  = idx & 3;
    const int ns  = idx >> 2;                 // mode0: 0..23, mode1: 0..7
    const int sel = (mode == 0) ? (ns >> 3) : 3;
    const int nn  = (mode == 0) ? (ns & 7) : ns;
    const int m0  = (xcd * 4 + mm) * 256;
    const int n0  = nn * 128;

    const unsigned short* Bmat = (sel == 0) ? w0 : (sel == 1) ? w1 : w2;
    const float* bias          = (sel == 0) ? b0 : (sel == 1) ? b1 : b2;
    const bool selV = (sel == 2);

    const int tid  = threadIdx.x;
    const int w    = tid >> 6;
    const int lane = tid & 63;
    const int l15  = lane & 15, g = lane >> 4;
    const int lane8 = lane * 8;
    const int wm8  = (w >> 2) * 8;    // A frag tg base (M half)
    const int wn2  = (w & 3) * 2;     // B frag tg base (N quarter of 32)

    __shared__ __align__(16) unsigned short As[2][32][512];   // 64 KB
    __shared__ __align__(16) unsigned short Bs[2][16][512];   // 32 KB

    f32x4 acc[8][2];
#pragma unroll
    for (int i = 0; i < 8; ++i)
#pragma unroll
        for (int j = 0; j < 2; ++j) acc[i][j] = (f32x4){0.f, 0.f, 0.f, 0.f};

    // per-thread global addresses of the 6 staging roles (advance kt*64)
    const unsigned short* aP[4];
#pragma unroll
    for (int j = 0; j < 4; ++j)
        aP[j] = Amat + (size_t)(m0 + (w >> 1) * 16 + 64 * j + l15) * D_
                     + (w & 1) * 32 + g * 8;
    const unsigned short* bP[2];
#pragma unroll
    for (int jb = 0; jb < 2; ++jb)
        bP[jb] = Bmat + (size_t)(n0 + w * 16 + l15) * D_ + jb * 32 + g * 8;

    // ---- prologue: K0 all 6 roles; K1 first set {A0,A2,B0,B1} ----
#pragma unroll
    for (int j = 0; j < 4; ++j) gl2lds16(aP[j], &As[0][w + 8 * j][0]);
    gl2lds16(bP[0], &Bs[0][2 * w    ][0]);
    gl2lds16(bP[1], &Bs[0][2 * w + 1][0]);
    gl2lds16(aP[0] + 64, &As[1][w     ][0]);
    gl2lds16(aP[2] + 64, &As[1][w + 16][0]);
    gl2lds16(bP[0] + 64, &Bs[1][2 * w    ][0]);
    gl2lds16(bP[1] + 64, &Bs[1][2 * w + 1][0]);
    asm volatile("s_waitcnt vmcnt(4)" ::: "memory");   // K0 landed
    __builtin_amdgcn_s_barrier();

    bf16x8 bfr[2][2];
    bf16x8 ap[4][2];

    for (int kt = 0; kt < NT8; ++kt) {
        const int cur = kt & 1;
        const int ko  = kt * 64;

        // ---------- phase 0: B frags + A mi0-3; stage kt+1 {A1,A3} ----------
#pragma unroll
        for (int nj = 0; nj < 2; ++nj)
#pragma unroll
            for (int ks = 0; ks < 2; ++ks)
                bfr[nj][ks] = *(const bf16x8*)&Bs[cur][(wn2 + nj) * 2 + ks][lane8];
#pragma unroll
        for (int mi = 0; mi < 4; ++mi)
#pragma unroll
            for (int ks = 0; ks < 2; ++ks)
                ap[mi][ks] = *(const bf16x8*)&As[cur][(wm8 + mi) * 2 + ks][lane8];
        if (kt + 1 < NT8) {
            gl2lds16(aP[1] + ko + 64, &As[cur ^ 1][w + 8 ][0]);
            gl2lds16(aP[3] + ko + 64, &As[cur ^ 1][w + 24][0]);
        }
        __builtin_amdgcn_s_barrier();
        asm volatile("s_waitcnt lgkmcnt(0)" ::: "memory");
        __builtin_amdgcn_s_setprio(1);
        if (!selV) {
#pragma unroll
            for (int mi = 0; mi < 4; ++mi)
#pragma unroll
                for (int nj = 0; nj < 2; ++nj) {
                    acc[mi][nj] = __builtin_amdgcn_mfma_f32_16x16x32_bf16(
                        bfr[nj][0], ap[mi][0], acc[mi][nj], 0, 0, 0);
                    acc[mi][nj] = __builtin_amdgcn_mfma_f32_16x16x32_bf16(
                        bfr[nj][1], ap[mi][1], acc[mi][nj], 0, 0, 0);
                }
        } else {
#pragma unroll
            for (int mi = 0; mi < 4; ++mi)
#pragma unroll
                for (int nj = 0; nj < 2; ++nj) {
                    acc[mi][nj] = __builtin_amdgcn_mfma_f32_16x16x32_bf16(
                        ap[mi][0], bfr[nj][0], acc[mi][nj], 0, 0, 0);
                    acc[mi][nj] = __builtin_amdgcn_mfma_f32_16x16x32_bf16(
                        ap[mi][1], bfr[nj][1], acc[mi][nj], 0, 0, 0);
                }
        }
        __builtin_amdgcn_s_setprio(0);
        __builtin_amdgcn_s_barrier();

        // ---------- phase 1: A mi4-7; stage kt+2 {A0,A2,B0,B1} ----------
#pragma unroll
        for (int mi = 0; mi < 4; ++mi)
#pragma unroll
            for (int ks = 0; ks < 2; ++ks)
                ap[mi][ks] = *(const bf16x8*)&As[cur][(wm8 + 4 + mi) * 2 + ks][lane8];
        if (kt + 2 < NT8) {
            gl2lds16(aP[0] + ko + 128, &As[cur][w     ][0]);
            gl2lds16(aP[2] + ko + 128, &As[cur][w + 16][0]);
            gl2lds16(bP[0] + ko + 128, &Bs[cur][2 * w    ][0]);
            gl2lds16(bP[1] + ko + 128, &Bs[cur][2 * w + 1][0]);
        }
        __builtin_amdgcn_s_barrier();
        asm volatile("s_waitcnt lgkmcnt(0)" ::: "memory");
        __builtin_amdgcn_s_setprio(1);
        if (!selV) {
#pragma unroll
            for (int mi = 0; mi < 4; ++mi)
#pragma unroll
                for (int nj = 0; nj < 2; ++nj) {
                    acc[4 + mi][nj] = __builtin_amdgcn_mfma_f32_16x16x32_bf16(
                        bfr[nj][0], ap[mi][0], acc[4 + mi][nj], 0, 0, 0);
                    acc[4 + mi][nj] = __builtin_amdgcn_mfma_f32_16x16x32_bf16(
                        bfr[nj][1], ap[mi][1], acc[4 + mi][nj], 0, 0, 0);
                }
        } else {
#pragma unroll
            for (int mi = 0; mi < 4; ++mi)
#pragma unroll
                for (int nj = 0; nj < 2; ++nj) {
                    acc[4 + mi][nj] = __builtin_amdgcn_mfma_f32_16x16x32_bf16(
                        ap[mi][0], bfr[nj][0], acc[4 + mi][nj], 0, 0, 0);
                    acc[4 + mi][nj] = __builtin_amdgcn_mfma_f32_16x16x32_bf16(
                        ap[mi][1], bfr[nj][1], acc[4 + mi][nj], 0, 0, 0);
                }
        }
        __builtin_amdgcn_s_setprio(0);
        if (kt < NT8 - 2)       asm volatile("s_waitcnt vmcnt(4)" ::: "memory");
        else if (kt == NT8 - 2) asm volatile("s_waitcnt vmcnt(0)" ::: "memory");
        __builtin_amdgcn_s_barrier();
    }

    // ---- epilogue ----
    const int mbase = m0 + (w >> 2) * 128;
    const int nbase = n0 + (w & 3) * 32;
    const size_t BTD = (size_t)B_ * T_ * D_;

    if (mode == 1) {
        // out-proj: fp32, token = l15, channel = g*4+reg
#pragma unroll
        for (int nj = 0; nj < 2; ++nj) {
            const int ch0 = nbase + nj * 16 + g * 4;
            const float4 bb = *(const float4*)(bias + ch0);
#pragma unroll
            for (int mi = 0; mi < 8; ++mi) {
                const int tok = mbase + mi * 16 + l15;
                float4 r;
                r.x = acc[mi][nj][0] + bb.x;
                r.y = acc[mi][nj][1] + bb.y;
                r.z = acc[mi][nj][2] + bb.z;
                r.w = acc[mi][nj][3] + bb.w;
                *(float4*)(outF + (size_t)tok * D_ + ch0) = r;
            }
        }
    } else if (!selV) {
        // Q/K: [bh][t][dk], token = l15, channel = g*4+reg; Q pre-scaled
        unsigned short* outp = outU + (size_t)sel * BTD;
        const float osc = (sel == 0) ? 0.125f * 1.44269504f : 1.0f;
#pragma unroll
        for (int nj = 0; nj < 2; ++nj) {
            const int ch0 = nbase + nj * 16 + g * 4;
            const int hh = ch0 >> 6, dk0 = ch0 & 63;
            const float4 bb = *(const float4*)(bias + ch0);
#pragma unroll
            for (int mi = 0; mi < 8; ++mi) {
                const int tok = mbase + mi * 16 + l15;
                const int b = tok >> 11, t = tok & (T_ - 1);
                ushort4 r;
                r.x = f2bf((acc[mi][nj][0] + bb.x) * osc);
                r.y = f2bf((acc[mi][nj][1] + bb.y) * osc);
                r.z = f2bf((acc[mi][nj][2] + bb.z) * osc);
                r.w = f2bf((acc[mi][nj][3] + bb.w) * osc);
                *(ushort4*)(outp + ((size_t)((b * H_ + hh) * T_ + t)) * DK_ + dk0) = r;
            }
        }
    } else {
        // V^T: [bh][dk][t], channel = l15, token = g*4+reg
        unsigned short* outp = outU + 2 * BTD;
#pragma unroll
        for (int nj = 0; nj < 2; ++nj) {
            const int ch = nbase + nj * 16 + l15;
            const int hh = ch >> 6, dk = ch & 63;
            const float bbv = bias[ch];
#pragma unroll
            for (int mi = 0; mi < 8; ++mi) {
                const int tok0 = mbase + mi * 16 + g * 4;
                const int b = tok0 >> 11, t0 = tok0 & (T_ - 1);
                ushort4 r;
                r.x = f2bf(acc[mi][nj][0] + bbv);
                r.y = f2bf(acc[mi][nj][1] + bbv);
                r.z = f2bf(acc[mi][nj][2] + bbv);
                r.w = f2bf(acc[mi][nj][3] + bbv);
                *(ushort4*)(outp + ((size_t)((b * H_ + hh) * DK_ + dk)) * T_ + t0) = r;
            }
        }
    }
}

// ---------------------------------------------------------------------------
// MFMA flash attention, R8: R6 chunk loop (4 waves x 16 q, LDS K/V staging +
// register prefetch, XCD-pinned — all measured-good) with split-K REMOVED:
// 32 single-pass blocks per bh (block x covers keys 0..(x+1)*64), heavy-first
// so the 32-chunk block starts first and is absorbed. Eliminates 33.5 MB fp32
// partial writes + the attn_reduce dispatch. T5 setprio around the PV MFMA
// cluster (+4-7% measured on attn, m191).
// ---------------------------------------------------------------------------
__global__ __launch_bounds__(256) void attn(
    const unsigned short* __restrict__ qg, const unsigned short* __restrict__ kg,
    const unsigned short* __restrict__ vtg,
    unsigned short* __restrict__ yh)
{
    // XCD-pinned mapping: xcd = s&7 owns bh in {xcd*8..xcd*8+7}, bh-major,
    // heavy-first within bh.
    const int s    = blockIdx.x;          // 0..2047
    const int xcd  = s & 7;
    const int t_   = s >> 3;              // 0..255
    const int bhl  = t_ >> 5;             // 0..7
    const int j    = t_ & 31;
    const int bh   = xcd * 8 + bhl;
    const int x    = 31 - j;              // heavy-first
    const int h    = bh & (H_ - 1);
    const int b    = bh >> 4;
    const int tq0  = x * 64;
    const int nCh  = x + 1;               // keys 0..tq0+63, 64-wide chunks

    const int tid  = threadIdx.x;
    const int w    = tid >> 6;
    const int lane = tid & 63;
    const int l15  = lane & 15;
    const int g    = lane >> 4;

    const size_t base = (size_t)bh * T_ * DK_;
    const unsigned short* Qb  = qg  + base;   // [t][dk], pre-scaled
    const unsigned short* Kb  = kg  + base;   // [t][dk]
    const unsigned short* Vtb = vtg + base;   // [dk][t]

    __shared__ __align__(16) unsigned short Kf[8][512];     // 8 KB
    __shared__ __align__(16) unsigned short Vf[8][512];     // 8 KB
    __shared__ __align__(16) unsigned short Pb[4][16][68];  // 8.7 KB

    const int q0w = tq0 + w * 16;
    const int tq  = q0w + l15;

    bf16x8 qf0 = *(const bf16x8*)(Qb + (size_t)tq * DK_ + g * 8);
    bf16x8 qf1 = *(const bf16x8*)(Qb + (size_t)tq * DK_ + 32 + g * 8);

    // all-ones A fragment (bf16 1.0 = 0x3F80) for the l-sum MFMA
    bf16x8 ones;
#pragma unroll
    for (int jj = 0; jj < 8; ++jj) ones[jj] = (short)0x3F80;

    f32x4 o[4];
#pragma unroll
    for (int i = 0; i < 4; ++i) o[i] = (f32x4){0.f, 0.f, 0.f, 0.f};
    f32x4 lacc = {0.f, 0.f, 0.f, 0.f};

    // wave w stages K s-tile st=w and V d-tile dt=w (both 32-wide halves)
    const unsigned short* kSrc = Kb + (size_t)(w * 16 + l15) * DK_ + g * 8;
    const unsigned short* vSrc = Vtb + (size_t)(w * 16 + l15) * T_ + g * 8;

    // preload chunk 0 into registers
    bf16x8 kr0 = *(const bf16x8*)(kSrc);
    bf16x8 kr1 = *(const bf16x8*)(kSrc + 32);
    bf16x8 vr0 = *(const bf16x8*)(vSrc);
    bf16x8 vr1 = *(const bf16x8*)(vSrc + 32);

    for (int ch = 0; ch < nCh; ++ch) {
        const int s0 = ch * 64;
        __syncthreads();                       // previous chunk fully consumed
        *(bf16x8*)&Kf[2 * w    ][lane * 8] = kr0;
        *(bf16x8*)&Kf[2 * w + 1][lane * 8] = kr1;
        *(bf16x8*)&Vf[2 * w    ][lane * 8] = vr0;
        *(bf16x8*)&Vf[2 * w + 1][lane * 8] = vr1;
        if (ch + 1 < nCh) {                    // loads stay in flight across barrier
            const size_t ko = (size_t)(ch + 1) * 64 * DK_;
            const int    vo = (ch + 1) * 64;
            kr0 = *(const bf16x8*)(kSrc + ko);
            kr1 = *(const bf16x8*)(kSrc + ko + 32);
            vr0 = *(const bf16x8*)(vSrc + vo);
            vr1 = *(const bf16x8*)(vSrc + vo + 32);
        }
        __syncthreads();                       // staged data visible

#pragma unroll
        for (int st = 0; st < 4; ++st) {
            const int sbase = s0 + st * 16;
            const bool live = (sbase <= q0w + 15);
            unsigned int pkl, pkh;
            if (live) {
                bf16x8 a0 = *(const bf16x8*)&Kf[st * 2 + 0][lane * 8];
                bf16x8 a1 = *(const bf16x8*)&Kf[st * 2 + 1][lane * 8];
                f32x4 sacc = {0.f, 0.f, 0.f, 0.f};
                sacc = __builtin_amdgcn_mfma_f32_16x16x32_bf16(a0, qf0, sacc, 0, 0, 0);
                sacc = __builtin_amdgcn_mfma_f32_16x16x32_bf16(a1, qf1, sacc, 0, 0, 0);
                float p0, p1, p2, p3;
                if (sbase + 15 > q0w) {        // diagonal tile: per-entry mask
                    p0 = (sbase + g * 4 + 0 <= tq) ? exp2f(sacc[0]) : 0.f;
                    p1 = (sbase + g * 4 + 1 <= tq) ? exp2f(sacc[1]) : 0.f;
                    p2 = (sbase + g * 4 + 2 <= tq) ? exp2f(sacc[2]) : 0.f;
                    p3 = (sbase + g * 4 + 3 <= tq) ? exp2f(sacc[3]) : 0.f;
                } else {                       // fully unmasked
                    p0 = exp2f(sacc[0]); p1 = exp2f(sacc[1]);
                    p2 = exp2f(sacc[2]); p3 = exp2f(sacc[3]);
                }
                pkl = pk2bf(p0, p1);
                pkh = pk2bf(p2, p3);
            } else {
                pkl = 0; pkh = 0;
            }
            uint2 pk; pk.x = pkl; pk.y = pkh;
            *(uint2*)&Pb[w][l15][st * 16 + g * 4] = pk;     // P[q][s], s-contig
        }

        bf16x8 pf0 = *(const bf16x8*)&Pb[w][l15][g * 8];        // k = s 0..31
        bf16x8 pf1 = *(const bf16x8*)&Pb[w][l15][32 + g * 8];   // k = s 32..63
        __builtin_amdgcn_s_setprio(1);
        lacc = __builtin_amdgcn_mfma_f32_16x16x32_bf16(ones, pf0, lacc, 0, 0, 0);
        lacc = __builtin_amdgcn_mfma_f32_16x16x32_bf16(ones, pf1, lacc, 0, 0, 0);
#pragma unroll
        for (int dt = 0; dt < 4; ++dt) {
            bf16x8 v0 = *(const bf16x8*)&Vf[dt * 2 + 0][lane * 8];
            bf16x8 v1 = *(const bf16x8*)&Vf[dt * 2 + 1][lane * 8];
            o[dt] = __builtin_amdgcn_mfma_f32_16x16x32_bf16(v0, pf0, o[dt], 0, 0, 0);
            o[dt] = __builtin_amdgcn_mfma_f32_16x16x32_bf16(v1, pf1, o[dt], 0, 0, 0);
        }
        __builtin_amdgcn_s_setprio(0);
    }

    // normalize and write yh bf16 directly (always single-pass now)
    const float inv = 1.f / lacc[0];
    unsigned short* yrow = yh + ((size_t)(b * T_ + tq)) * D_ + h * DK_;
#pragma unroll
    for (int dt = 0; dt < 4; ++dt) {
        ushort4 r;
        r.x = f2bf(o[dt][0] * inv); r.y = f2bf(o[dt][1] * inv);
        r.z = f2bf(o[dt][2] * inv); r.w = f2bf(o[dt][3] * inv);
        *(ushort4*)(yrow + dt * 16 + g * 4) = r;
    }
}

// ---------------------------------------------------------------------------
extern "C" void kernel_launch(void* const* d_in, const int* in_sizes, int n_in,
                              void* d_out, int out_size, void* d_ws, size_t ws_size,
                              hipStream_t stream) {
    const float* x  = (const float*)d_in[0];
    const float* wq = (const float*)d_in[1];
    const float* bq = (const float*)d_in[2];
    const float* wk = (const float*)d_in[3];
    const float* bk = (const float*)d_in[4];
    const float* wv = (const float*)d_in[5];
    const float* bv = (const float*)d_in[6];
    const float* wo = (const float*)d_in[7];
    const float* bo = (const float*)d_in[8];
    float* out = (float*)d_out;

    const size_t BTD = (size_t)B_ * T_ * D_;          // 8388608
    const size_t WSZ = (size_t)D_ * D_;               // 1048576
    unsigned short* xb  = (unsigned short*)d_ws;      // [x | wq | wk | wv | wo] bf16
    unsigned short* wqb = xb  + BTD;
    unsigned short* wkb = wqb + WSZ;
    unsigned short* wvb = wkb + WSZ;
    unsigned short* wob = wvb + WSZ;
    unsigned short* qb  = wob + WSZ;                  // q | k | vt bf16
    unsigned short* kb  = qb  + BTD;
    unsigned short* vtb = kb  + BTD;
    unsigned short* yhb = vtb + BTD;                  // yh bf16 [B,T,D]

    cvt_bf16<<<dim3(12288), 256, 0, stream>>>(x, wq, wk, wv, wo, xb);

    // QKV: 8 xcd-chunks x 4 m x (8 n x 3 sel) = 768 blocks = exactly 3 rounds
    gemm8p<<<dim3(768), 512, 0, stream>>>(
        xb, wqb, wkb, wvb, bq, bk, bv, qb, (float*)nullptr, 0);

    // attn: 2048 blocks (32 per bh), XCD-pinned, heavy-first, single-pass
    attn<<<dim3(2048), 256, 0, stream>>>(qb, kb, vtb, yhb);

    // out-proj: 8 x 4 x 8 = 256 blocks = exactly 1 round
    gemm8p<<<dim3(256), 512, 0, stream>>>(
        yhb, wob, wob, wob, bo, bo, bo, (unsigned short*)nullptr, out, 1);
}